// Round 11
// baseline (1214.713 us; speedup 1.0000x reference)
//
#include <hip/hip_runtime.h>

typedef __attribute__((ext_vector_type(8))) short short8;
typedef __attribute__((ext_vector_type(4))) float floatx4;

#define N_PF 60000
#define N_GW 300000
#define N_SW 60000
#define EPT 1000000          // edges per (non-self) edge type
#define TOTE 7000000
#define L_CNT 1140000        // concat of 7 per-dst count arrays
#define SPAN 4096            // concat indices per radix bucket
#define N_B 279              // ceil(L_CNT / SPAN)
#define CHSZ 4096            // edges per partition chunk
#define NCH 1709             // ceil(TOTE / CHSZ)

__device__ __forceinline__ unsigned short f2bf(float f) {
  unsigned u = __float_as_uint(f);
  u = (u + 0x7FFF + ((u >> 16) & 1)) >> 16;
  return (unsigned short)u;
}
__device__ __forceinline__ float bf2f(unsigned short u) {
  return __uint_as_float((unsigned)u << 16);
}
__device__ __forceinline__ void acc8(float* a, short8 v) {
#pragma unroll
  for (int k = 0; k < 8; ++k) a[k] += bf2f((unsigned short)v[k]);
}

__device__ __forceinline__ int cnt_base(int et) {
  switch (et) {
    case 0: return 0;
    case 1: return 300000;
    case 2: return 360000;
    case 3: return 420000;
    case 4: return 480000;
    case 5: return 780000;
    default: return 840000;
  }
}

__device__ __forceinline__ const int* pick(const int* e0, const int* e1,
                                           const int* e2, const int* e3,
                                           const int* e4, const int* e5,
                                           const int* e6, int et) {
  switch (et) {
    case 0: return e0; case 1: return e1; case 2: return e2; case 3: return e3;
    case 4: return e4; case 5: return e5; default: return e6;
  }
}

// ---------------- input cast f32 -> bf16 ----------------
__global__ __launch_bounds__(256) void k_cast(const float4* __restrict__ x,
                                              ushort4* __restrict__ xb, int n4) {
  int i = blockIdx.x * 256 + threadIdx.x;
  if (i < n4) {
    float4 v = x[i];
    ushort4 o;
    o.x = f2bf(v.x); o.y = f2bf(v.y); o.z = f2bf(v.z); o.w = f2bf(v.w);
    xb[i] = o;
  }
}

// ============ CSR build via two-level radix partition ====
// part[] entries are 4B: (local_idx:12 << 19) | src:19  (src < 2^19 always;
// slot bits unused by k_layer; 56MB->28MB partition traffic)

// Pass 1: per-chunk bucket histogram -> hcnt[bucket][chunk]
__global__ __launch_bounds__(256) void k_h1(
    const int* e0, const int* e1, const int* e2, const int* e3,
    const int* e4, const int* e5, const int* e6, int* __restrict__ hcnt) {
  __shared__ int hist[N_B];
  int ch = blockIdx.x, t = threadIdx.x;
  for (int i = t; i < N_B; i += 256) hist[i] = 0;
  __syncthreads();
  int base = ch * CHSZ;
  int nn = TOTE - base; if (nn > CHSZ) nn = CHSZ;
#pragma unroll
  for (int u = 0; u < CHSZ / 256; ++u) {
    int o = u * 256 + t;
    if (o < nn) {
      int gid = base + o;
      int et = gid / EPT, i2 = gid - et * EPT;
      const int* ei = pick(e0, e1, e2, e3, e4, e5, e6, et);
      int idx = cnt_base(et) + ei[EPT + i2];
      atomicAdd(&hist[idx >> 12], 1);
    }
  }
  __syncthreads();
  for (int b = t; b < N_B; b += 256) hcnt[(size_t)b * NCH + ch] = hist[b];
}

// Pass 2a: bucket totals (column reduce)
__global__ __launch_bounds__(256) void k_h2a(const int* __restrict__ hcnt,
                                             int* __restrict__ btot) {
  __shared__ int sh[4];
  int b = blockIdx.x;
  const int* c = hcnt + (size_t)b * NCH;
  int s = 0;
  for (int k = threadIdx.x; k < NCH; k += 256) s += c[k];
  for (int off = 1; off < 64; off <<= 1) s += __shfl_xor(s, off, 64);
  int lane = threadIdx.x & 63, w = threadIdx.x >> 6;
  if (lane == 0) sh[w] = s;
  __syncthreads();
  if (threadIdx.x == 0) btot[b] = sh[0] + sh[1] + sh[2] + sh[3];
}

// Pass 2b: exclusive scan of 279 bucket totals (one wave) + sentinel
__global__ __launch_bounds__(64) void k_h2b(const int* __restrict__ btot,
                                            int* __restrict__ bbase,
                                            int* __restrict__ Sarr) {
  int lane = threadIdx.x;
  int v[5]; int s = 0;
#pragma unroll
  for (int k = 0; k < 5; ++k) {
    int i = lane * 5 + k;
    v[k] = (i < N_B) ? btot[i] : 0;
    s += v[k];
  }
  int x = s;
  for (int off = 1; off < 64; off <<= 1) {
    int tv = __shfl_up(x, off, 64);
    if (lane >= off) x += tv;
  }
  int run = x - s;
#pragma unroll
  for (int k = 0; k < 5; ++k) {
    int i = lane * 5 + k;
    if (i < N_B) bbase[i] = run;
    run += v[k];
  }
  if (lane == 63) { bbase[N_B] = x; Sarr[L_CNT] = TOTE; }
}

// Pass 2c: column scan -> per (chunk,bucket) global base (deterministic)
__global__ __launch_bounds__(256) void k_h2c(int* __restrict__ hcnt,
                                             const int* __restrict__ bbase) {
  __shared__ int sc[256];
  int b = blockIdx.x, t = threadIdx.x;
  int* c = hcnt + (size_t)b * NCH;
  int v[7]; int s = 0;
#pragma unroll
  for (int k = 0; k < 7; ++k) {
    int i = t * 7 + k;
    v[k] = (i < NCH) ? c[i] : 0;
    s += v[k];
  }
  sc[t] = s;
  __syncthreads();
  for (int off = 1; off < 256; off <<= 1) {
    int tv = (t >= off) ? sc[t - off] : 0;
    __syncthreads();
    sc[t] += tv;
    __syncthreads();
  }
  int run = bbase[b] + sc[t] - s;
#pragma unroll
  for (int k = 0; k < 7; ++k) {
    int i = t * 7 + k;
    if (i < NCH) { int vv = v[k]; c[i] = run; run += vv; }
  }
}

// Pass 3: partition edges into bucket-contiguous part[] via LDS chunk sort.
__global__ __launch_bounds__(256) void k_bfill(
    const int* e0, const int* e1, const int* e2, const int* e3,
    const int* e4, const int* e5, const int* e6,
    const int* __restrict__ hcnt, unsigned* __restrict__ part) {
  __shared__ int hist[N_B];
  __shared__ int segs[N_B];
  __shared__ int curb[N_B];
  __shared__ int gbase[N_B];
  __shared__ int sc[256];
  __shared__ unsigned long long stg[CHSZ];
  int ch = blockIdx.x, t = threadIdx.x;
  for (int i = t; i < N_B; i += 256) hist[i] = 0;
  __syncthreads();
  int base = ch * CHSZ;
  int nn = TOTE - base; if (nn > CHSZ) nn = CHSZ;
#pragma unroll
  for (int u = 0; u < CHSZ / 256; ++u) {
    int o = u * 256 + t;
    if (o < nn) {
      int gid = base + o;
      int et = gid / EPT, i2 = gid - et * EPT;
      const int* ei = pick(e0, e1, e2, e3, e4, e5, e6, et);
      int idx = cnt_base(et) + ei[EPT + i2];
      atomicAdd(&hist[idx >> 12], 1);
    }
  }
  __syncthreads();
  int v0 = (2 * t < N_B) ? hist[2 * t] : 0;
  int v1 = (2 * t + 1 < N_B) ? hist[2 * t + 1] : 0;
  int s = v0 + v1;
  sc[t] = s;
  __syncthreads();
  for (int off = 1; off < 256; off <<= 1) {
    int tv = (t >= off) ? sc[t - off] : 0;
    __syncthreads();
    sc[t] += tv;
    __syncthreads();
  }
  int excl = sc[t] - s;
  if (2 * t < N_B) { segs[2 * t] = excl; curb[2 * t] = excl; }
  if (2 * t + 1 < N_B) { segs[2 * t + 1] = excl + v0; curb[2 * t + 1] = excl + v0; }
  for (int b = t; b < N_B; b += 256) gbase[b] = hcnt[(size_t)b * NCH + ch];
  __syncthreads();
#pragma unroll
  for (int u = 0; u < CHSZ / 256; ++u) {
    int o = u * 256 + t;
    if (o < nn) {
      int gid = base + o;
      int et = gid / EPT, i2 = gid - et * EPT;
      const int* ei = pick(e0, e1, e2, e3, e4, e5, e6, et);
      int dst = ei[EPT + i2];
      int src = ei[i2];
      int idx = cnt_base(et) + dst;
      unsigned long long p = ((unsigned long long)idx << 32) | (unsigned)src;
      int r = atomicAdd(&curb[idx >> 12], 1);
      stg[r] = p;
    }
  }
  __syncthreads();
  for (int sdx = t; sdx < nn; sdx += 256) {
    unsigned long long p = stg[sdx];
    int idx = (int)(p >> 32);
    int b = idx >> 12;
    unsigned ent = ((unsigned)(idx & 4095) << 19) | (unsigned)(p & 0x7FFFF);
    part[(size_t)gbase[b] + (sdx - segs[b])] = ent;
  }
}

// Pass 4: one 1024-thread block per bucket; wave-shuffle scan; int4 hist.
__global__ __launch_bounds__(1024) void k_cfill(
    const unsigned* __restrict__ part, const int* __restrict__ bbase,
    int* __restrict__ Sarr, int* __restrict__ col) {
  __shared__ int hist[SPAN];
  __shared__ int wt[16];
  int t = threadIdx.x;
  int lane = t & 63, wv = t >> 6;
  int b = blockIdx.x;
  int lo = b * SPAN;
  int span_n = L_CNT - lo; if (span_n > SPAN) span_n = SPAN;
  int s0 = bbase[b], s1 = bbase[b + 1];
  ((int4*)hist)[t] = (int4){0, 0, 0, 0};
  __syncthreads();
  for (int j = s0 + t; j < s1; j += 1024) {
    int local = (int)(part[j] >> 19);
    atomicAdd(&hist[local], 1);
  }
  __syncthreads();
  int4 v = ((int4*)hist)[t];
  int s = v.x + v.y + v.z + v.w;
  int x = s;
#pragma unroll
  for (int off = 1; off < 64; off <<= 1) {
    int tv = __shfl_up(x, off, 64);
    if (lane >= off) x += tv;
  }
  if (lane == 63) wt[wv] = x;
  __syncthreads();
  int woff = 0;
#pragma unroll
  for (int k = 0; k < 16; ++k) woff += (k < wv) ? wt[k] : 0;
  int run = woff + x - s;
  int4 cur4, sa4;
  cur4.x = run; sa4.x = s0 + run; run += v.x;
  cur4.y = run; sa4.y = s0 + run; run += v.y;
  cur4.z = run; sa4.z = s0 + run; run += v.z;
  cur4.w = run; sa4.w = s0 + run; run += v.w;
  __syncthreads();
  ((int4*)hist)[t] = cur4;
  if (t * 4 + 3 < span_n) {
    *(int4*)(&Sarr[lo + t * 4]) = sa4;
  } else {
    if (t * 4 + 0 < span_n) Sarr[lo + t * 4 + 0] = sa4.x;
    if (t * 4 + 1 < span_n) Sarr[lo + t * 4 + 1] = sa4.y;
    if (t * 4 + 2 < span_n) Sarr[lo + t * 4 + 2] = sa4.z;
  }
  __syncthreads();
  for (int j = s0 + t; j < s1; j += 1024) {
    unsigned p = part[j];
    int local = (int)(p >> 19);
    int r = atomicAdd(&hist[local], 1);
    col[s0 + r] = (int)(p & 0x7FFFF);
  }
}

// ---------------- weight prep (fold + swizzle -> bf16) ----------------
template <int KIN, int NE>
__global__ __launch_bounds__(256) void k_prep(
    const float* __restrict__ Wl, const float* __restrict__ Wr,
    const float* __restrict__ bl, int e0, int e1, int e2, int es,
    unsigned short* __restrict__ wsw, float* __restrict__ bias) {
  constexpr int KCAT = (NE + 1) * KIN;
  int idx = blockIdx.x * 256 + threadIdx.x;
  if (idx < KCAT * 64) {
    int j = idx & 7, lane = (idx >> 3) & 63, t = idx >> 9;
    int ct = t & 3, kc = t >> 2;
    int k = kc * 32 + ((lane >> 4) << 3) + j;
    int c = ct * 16 + (lane & 15);
    int seg = k / KIN, kk = k - seg * KIN;
    float v;
    if (seg < NE) {
      int e = (seg == 0) ? e0 : (seg == 1) ? e1 : e2;
      v = Wl[((size_t)e * 64 + c) * KIN + kk];
    } else {
      v = Wl[((size_t)es * 64 + c) * KIN + kk] +
          Wr[((size_t)es * 64 + c) * KIN + kk] +
          Wr[((size_t)e0 * 64 + c) * KIN + kk] +
          Wr[((size_t)e1 * 64 + c) * KIN + kk];
      if (NE == 3) v += Wr[((size_t)e2 * 64 + c) * KIN + kk];
    }
    wsw[idx] = f2bf(v);
  } else if (idx < KCAT * 64 + 64) {
    int c = idx - KCAT * 64;
    float v = bl[e0 * 64 + c] + bl[e1 * 64 + c] + bl[es * 64 + c];
    if (NE == 3) v += bl[e2 * 64 + c];
    bias[c] = v;
  }
}

// ------- fused gather(mean,bf16) + MFMA + bias + ReLU [+lin] -------
// R10 lesson: NE chains per node ran serially (chain startup = Sarr->col->row
// ~700cyc dominates at mean degree 3.3). Now chains run in LOCKSTEP rounds:
// each round issues col+2 row loads for EVERY unfinished chain (2*NE loads in
// flight), trip count = max-degree not sum-of-degrees.
// OMODE: 0 = store bf16 h, 1 = store f32 h, 2 = fused linear+PReLU -> f32 out
template <int KIN, int NE, int OMODE>
__global__ __launch_bounds__(256) void k_layer(
    const int* __restrict__ Sarr, const int* __restrict__ col,
    const unsigned short* __restrict__ s0, const unsigned short* __restrict__ s1,
    const unsigned short* __restrict__ s2, int b0, int b1, int b2,
    const unsigned short* __restrict__ xD,
    const unsigned short* __restrict__ wsw, const float* __restrict__ bias,
    void* __restrict__ hOut, const float* __restrict__ linW,
    const float* __restrict__ linb, const float* __restrict__ pa, int Ndst) {
  constexpr int KCAT = (NE + 1) * KIN;
  constexpr int KCH = KCAT / 32;
  constexpr int ZSTR = KCAT + 8;
  constexpr int LPR = KIN / 8;     // lanes per feature row (8 or 4)
  constexpr int G = 64 / LPR;      // node-groups per wave (8 or 16)
  __shared__ unsigned short z[4 * 16 * ZSTR];
  const int lane = threadIdx.x & 63;
  unsigned short* zw = &z[(threadIdx.x >> 6) * 16 * ZSTR];
  const int wid = (blockIdx.x * 256 + threadIdx.x) >> 6;
  const int nw = (gridDim.x * 256) >> 6;
  const unsigned short* srcs[3] = {s0, s1, s2};
  const int bases[3] = {b0, b1, b2};
  const int cl = lane & 15, quad = lane >> 4;
  const int g = lane / LPR;
  const int c = lane % LPR;

  for (int nb = wid * 16; nb < Ndst; nb += nw * 16) {  // Ndst % 16 == 0
#pragma unroll
    for (int i0 = 0; i0 < 16; i0 += G) {
      int n = nb + i0 + g;
      unsigned short* zr = &zw[(i0 + g) * ZSTR];
      *(short8*)(&zr[NE * KIN + c * 8]) =
          *(const short8*)(xD + (size_t)n * KIN + c * 8);
      // ---- lockstep interleaved chains ----
      int jj[NE], tt[NE], cv[NE];
      float a0[NE][8], a1[NE][8];
#pragma unroll
      for (int e = 0; e < NE; ++e) {
        jj[e] = Sarr[bases[e] + n];
        tt[e] = Sarr[bases[e] + n + 1];  // sentinel-safe
        cv[e] = tt[e] - jj[e];
#pragma unroll
        for (int k = 0; k < 8; ++k) { a0[e][k] = 0.f; a1[e][k] = 0.f; }
      }
      bool more = true;
      while (more) {
        more = false;
#pragma unroll
        for (int e = 0; e < NE; ++e) {
          int j = jj[e];
          int rem = tt[e] - j;
          if (rem >= 2) {
            int r0 = col[j], r1 = col[j + 1];
            short8 v0 = *(const short8*)(srcs[e] + (size_t)r0 * KIN + c * 8);
            short8 v1 = *(const short8*)(srcs[e] + (size_t)r1 * KIN + c * 8);
            acc8(a0[e], v0);
            acc8(a1[e], v1);
            jj[e] = j + 2;
            if (rem > 2) more = true;
          } else if (rem == 1) {
            int r0 = col[j];
            short8 v0 = *(const short8*)(srcs[e] + (size_t)r0 * KIN + c * 8);
            acc8(a0[e], v0);
            jj[e] = j + 1;
          }
        }
      }
#pragma unroll
      for (int e = 0; e < NE; ++e) {
        int d = cv[e] < 1 ? 1 : cv[e];
        float inv = 1.0f / (float)d;
        short8 o;
#pragma unroll
        for (int k = 0; k < 8; ++k)
          o[k] = (short)f2bf((a0[e][k] + a1[e][k]) * inv);
        *(short8*)(&zr[e * KIN + c * 8]) = o;
      }
    }
    // ---- MFMA: 16 nodes x 64 out cols, K = KCAT ----
    floatx4 acc[4];
#pragma unroll
    for (int ct = 0; ct < 4; ++ct) {
      float bv = bias[ct * 16 + cl];
      acc[ct] = (floatx4){bv, bv, bv, bv};
    }
#pragma unroll
    for (int kc = 0; kc < KCH; ++kc) {
      short8 a = *(const short8*)(&zw[cl * ZSTR + kc * 32 + quad * 8]);
#pragma unroll
      for (int ct = 0; ct < 4; ++ct) {
        short8 b = *(const short8*)(wsw + ((size_t)(kc * 4 + ct) * 64 + lane) * 8);
        acc[ct] = __builtin_amdgcn_mfma_f32_16x16x32_bf16(a, b, acc[ct], 0, 0, 0);
      }
    }
    // ---- epilogue ----
    if (OMODE == 2) {
      float p[4] = {0.f, 0.f, 0.f, 0.f};
#pragma unroll
      for (int ct = 0; ct < 4; ++ct) {
        float w = linW[ct * 16 + cl];
#pragma unroll
        for (int r = 0; r < 4; ++r) {
          float v = acc[ct][r];
          v = v > 0.f ? v : 0.f;
          p[r] += v * w;
        }
      }
#pragma unroll
      for (int off = 1; off < 16; off <<= 1) {
#pragma unroll
        for (int r = 0; r < 4; ++r) p[r] += __shfl_xor(p[r], off, 64);
      }
      if (cl == 0) {
        float lb = linb[0], al = pa[0];
        float* o = (float*)hOut;
#pragma unroll
        for (int r = 0; r < 4; ++r) {
          int n = nb + quad * 4 + r;
          float v = p[r] + lb;
          o[n] = v >= 0.f ? v : al * v;
        }
      }
    } else {
#pragma unroll
      for (int ct = 0; ct < 4; ++ct)
#pragma unroll
        for (int r = 0; r < 4; ++r) {
          int n = nb + quad * 4 + r;
          float v = acc[ct][r];
          v = v > 0.f ? v : 0.f;
          if (OMODE == 1)
            ((float*)hOut)[(size_t)n * 64 + ct * 16 + cl] = v;
          else
            ((unsigned short*)hOut)[(size_t)n * 64 + ct * 16 + cl] = f2bf(v);
        }
    }
  }
}

extern "C" void kernel_launch(void* const* d_in, const int* in_sizes, int n_in,
                              void* d_out, int out_size, void* d_ws,
                              size_t ws_size, hipStream_t stream) {
  const float* x_pf = (const float*)d_in[0];
  const float* x_gw = (const float*)d_in[1];
  const float* x_sw = (const float*)d_in[2];
  const float* W1l = (const float*)d_in[3];
  const float* b1l = (const float*)d_in[4];
  const float* W1r = (const float*)d_in[5];
  const float* W2l = (const float*)d_in[6];
  const float* b2l = (const float*)d_in[7];
  const float* W2r = (const float*)d_in[8];
  const float* linW = (const float*)d_in[9];
  const float* linb = (const float*)d_in[10];
  const float* pa = (const float*)d_in[11];
  const int* e0 = (const int*)d_in[12];  // pf->gw
  const int* e1 = (const int*)d_in[13];  // gw->pf
  const int* e2 = (const int*)d_in[14];  // pf->sw
  const int* e3 = (const int*)d_in[15];  // sw->pf
  const int* e4 = (const int*)d_in[16];  // sw->gw
  const int* e5 = (const int*)d_in[17];  // gw->sw
  const int* e6 = (const int*)d_in[18];  // gw->gw
  float* out = (float*)d_out;

  char* w = (char*)d_ws;
  size_t off = 0;
  auto alloc = [&](size_t bytes) -> void* {
    void* p = w + off;
    off += bytes;
    off = (off + 255) & ~(size_t)255;
    return p;
  };
  unsigned* part = (unsigned*)alloc((size_t)TOTE * 4);     // 28MB (4B entries)
  int* col = (int*)alloc((size_t)TOTE * 4);                // 28MB
  int* Sarr = (int*)alloc((size_t)(L_CNT + 1) * 4);
  int* hcnt = (int*)alloc((size_t)N_B * NCH * 4);          // 1.9MB
  int* btot = (int*)alloc((N_B + 1) * 4);
  int* bbase = (int*)alloc((N_B + 1) * 4);
  unsigned short* xb_pf = (unsigned short*)alloc((size_t)N_PF * 32 * 2);
  unsigned short* xb_gw = (unsigned short*)alloc((size_t)N_GW * 32 * 2);
  unsigned short* xb_sw = (unsigned short*)alloc((size_t)N_SW * 32 * 2);
  unsigned short* h1_pf = (unsigned short*)alloc((size_t)N_PF * 64 * 2);
  unsigned short* h1_gw = (unsigned short*)alloc((size_t)N_GW * 64 * 2);
  unsigned short* h1_sw = (unsigned short*)alloc((size_t)N_SW * 64 * 2);
  unsigned short* w1gw = (unsigned short*)alloc(128 * 64 * 2);
  unsigned short* w1pf = (unsigned short*)alloc(96 * 64 * 2);
  unsigned short* w1sw = (unsigned short*)alloc(96 * 64 * 2);
  unsigned short* w2gw = (unsigned short*)alloc(256 * 64 * 2);
  unsigned short* w2pf = (unsigned short*)alloc(192 * 64 * 2);
  unsigned short* w2sw = (unsigned short*)alloc(192 * 64 * 2);
  float* bs1gw = (float*)alloc(64 * 4);
  float* bs1pf = (float*)alloc(64 * 4);
  float* bs1sw = (float*)alloc(64 * 4);
  float* bs2gw = (float*)alloc(64 * 4);
  float* bs2pf = (float*)alloc(64 * 4);
  float* bs2sw = (float*)alloc(64 * 4);

  // input casts
  k_cast<<<(N_PF * 8 + 255) / 256, 256, 0, stream>>>((const float4*)x_pf,
                                                     (ushort4*)xb_pf, N_PF * 8);
  k_cast<<<(N_GW * 8 + 255) / 256, 256, 0, stream>>>((const float4*)x_gw,
                                                     (ushort4*)xb_gw, N_GW * 8);
  k_cast<<<(N_SW * 8 + 255) / 256, 256, 0, stream>>>((const float4*)x_sw,
                                                     (ushort4*)xb_sw, N_SW * 8);

  // CSR build: radix partition (deterministic bases, no contended atomics)
  k_h1<<<NCH, 256, 0, stream>>>(e0, e1, e2, e3, e4, e5, e6, hcnt);
  k_h2a<<<N_B, 256, 0, stream>>>(hcnt, btot);
  k_h2b<<<1, 64, 0, stream>>>(btot, bbase, Sarr);
  k_h2c<<<N_B, 256, 0, stream>>>(hcnt, bbase);
  k_bfill<<<NCH, 256, 0, stream>>>(e0, e1, e2, e3, e4, e5, e6, hcnt, part);
  k_cfill<<<N_B, 1024, 0, stream>>>(part, bbase, Sarr, col);

  // weight prep
  k_prep<32, 3><<<(128 * 64 + 64 + 255) / 256, 256, 0, stream>>>(
      W1l, W1r, b1l, 0, 4, 6, 7, w1gw, bs1gw);
  k_prep<32, 2><<<(96 * 64 + 64 + 255) / 256, 256, 0, stream>>>(
      W1l, W1r, b1l, 1, 3, 0, 9, w1pf, bs1pf);
  k_prep<32, 2><<<(96 * 64 + 64 + 255) / 256, 256, 0, stream>>>(
      W1l, W1r, b1l, 2, 5, 0, 8, w1sw, bs1sw);
  k_prep<64, 3><<<(256 * 64 + 64 + 255) / 256, 256, 0, stream>>>(
      W2l, W2r, b2l, 0, 4, 6, 7, w2gw, bs2gw);
  k_prep<64, 2><<<(192 * 64 + 64 + 255) / 256, 256, 0, stream>>>(
      W2l, W2r, b2l, 1, 3, 0, 9, w2pf, bs2pf);
  k_prep<64, 2><<<(192 * 64 + 64 + 255) / 256, 256, 0, stream>>>(
      W2l, W2r, b2l, 2, 5, 0, 8, w2sw, bs2sw);

  // layer 1 (KIN=32, G=16) -> bf16 h1
  k_layer<32, 3, 0><<<1024, 256, 0, stream>>>(
      Sarr, col, xb_pf, xb_sw, xb_gw, 0, 480000, 840000, xb_gw, w1gw, bs1gw,
      h1_gw, nullptr, nullptr, nullptr, N_GW);
  k_layer<32, 2, 0><<<1024, 256, 0, stream>>>(
      Sarr, col, xb_gw, xb_sw, (const unsigned short*)nullptr, 300000, 420000,
      0, xb_pf, w1pf, bs1pf, h1_pf, nullptr, nullptr, nullptr, N_PF);
  k_layer<32, 2, 0><<<1024, 256, 0, stream>>>(
      Sarr, col, xb_pf, xb_gw, (const unsigned short*)nullptr, 360000, 780000,
      0, xb_sw, w1sw, bs1sw, h1_sw, nullptr, nullptr, nullptr, N_SW);

  // layer 2 (KIN=64, G=8): gw/sw fuse linear+PReLU; pf -> f32 h_pf out
  k_layer<64, 3, 2><<<1024, 256, 0, stream>>>(
      Sarr, col, h1_pf, h1_sw, h1_gw, 0, 480000, 840000, h1_gw, w2gw, bs2gw,
      out, linW, linb, pa, N_GW);
  k_layer<64, 2, 1><<<1024, 256, 0, stream>>>(
      Sarr, col, h1_gw, h1_sw, (const unsigned short*)nullptr, 300000, 420000,
      0, h1_pf, w2pf, bs2pf, out + 360000, nullptr, nullptr, nullptr, N_PF);
  k_layer<64, 2, 2><<<1024, 256, 0, stream>>>(
      Sarr, col, h1_pf, h1_gw, (const unsigned short*)nullptr, 360000, 780000,
      0, h1_sw, w2sw, bs2sw, out + N_GW, linW, linb, pa, N_SW);
}

// Round 12
// 697.823 us; speedup vs baseline: 1.7407x; 1.7407x over previous
//
#include <hip/hip_runtime.h>

typedef __attribute__((ext_vector_type(8))) short short8;
typedef __attribute__((ext_vector_type(4))) float floatx4;

#define N_PF 60000
#define N_GW 300000
#define N_SW 60000
#define EPT 1000000          // edges per (non-self) edge type
#define TOTE 7000000
#define L_CNT 1140000        // concat of 7 per-dst count arrays
#define SPAN 4096            // concat indices per radix bucket
#define N_B 279              // ceil(L_CNT / SPAN)
#define CHSZ 4096            // edges per partition chunk
#define NCH 1709             // ceil(TOTE / CHSZ)

__device__ __forceinline__ unsigned short f2bf(float f) {
  unsigned u = __float_as_uint(f);
  u = (u + 0x7FFF + ((u >> 16) & 1)) >> 16;
  return (unsigned short)u;
}
__device__ __forceinline__ float bf2f(unsigned short u) {
  return __uint_as_float((unsigned)u << 16);
}
__device__ __forceinline__ void acc8(float* a, short8 v) {
#pragma unroll
  for (int k = 0; k < 8; ++k) a[k] += bf2f((unsigned short)v[k]);
}

__device__ __forceinline__ int cnt_base(int et) {
  switch (et) {
    case 0: return 0;
    case 1: return 300000;
    case 2: return 360000;
    case 3: return 420000;
    case 4: return 480000;
    case 5: return 780000;
    default: return 840000;
  }
}

__device__ __forceinline__ const int* pick(const int* e0, const int* e1,
                                           const int* e2, const int* e3,
                                           const int* e4, const int* e5,
                                           const int* e6, int et) {
  switch (et) {
    case 0: return e0; case 1: return e1; case 2: return e2; case 3: return e3;
    case 4: return e4; case 5: return e5; default: return e6;
  }
}

// ---------------- input cast f32 -> bf16 ----------------
__global__ __launch_bounds__(256) void k_cast(const float4* __restrict__ x,
                                              ushort4* __restrict__ xb, int n4) {
  int i = blockIdx.x * 256 + threadIdx.x;
  if (i < n4) {
    float4 v = x[i];
    ushort4 o;
    o.x = f2bf(v.x); o.y = f2bf(v.y); o.z = f2bf(v.z); o.w = f2bf(v.w);
    xb[i] = o;
  }
}

// ============ CSR build via two-level radix partition (4B part entries) ====

__global__ __launch_bounds__(256) void k_h1(
    const int* e0, const int* e1, const int* e2, const int* e3,
    const int* e4, const int* e5, const int* e6, int* __restrict__ hcnt) {
  __shared__ int hist[N_B];
  int ch = blockIdx.x, t = threadIdx.x;
  for (int i = t; i < N_B; i += 256) hist[i] = 0;
  __syncthreads();
  int base = ch * CHSZ;
  int nn = TOTE - base; if (nn > CHSZ) nn = CHSZ;
#pragma unroll
  for (int u = 0; u < CHSZ / 256; ++u) {
    int o = u * 256 + t;
    if (o < nn) {
      int gid = base + o;
      int et = gid / EPT, i2 = gid - et * EPT;
      const int* ei = pick(e0, e1, e2, e3, e4, e5, e6, et);
      int idx = cnt_base(et) + ei[EPT + i2];
      atomicAdd(&hist[idx >> 12], 1);
    }
  }
  __syncthreads();
  for (int b = t; b < N_B; b += 256) hcnt[(size_t)b * NCH + ch] = hist[b];
}

__global__ __launch_bounds__(256) void k_h2a(const int* __restrict__ hcnt,
                                             int* __restrict__ btot) {
  __shared__ int sh[4];
  int b = blockIdx.x;
  const int* c = hcnt + (size_t)b * NCH;
  int s = 0;
  for (int k = threadIdx.x; k < NCH; k += 256) s += c[k];
  for (int off = 1; off < 64; off <<= 1) s += __shfl_xor(s, off, 64);
  int lane = threadIdx.x & 63, w = threadIdx.x >> 6;
  if (lane == 0) sh[w] = s;
  __syncthreads();
  if (threadIdx.x == 0) btot[b] = sh[0] + sh[1] + sh[2] + sh[3];
}

__global__ __launch_bounds__(64) void k_h2b(const int* __restrict__ btot,
                                            int* __restrict__ bbase,
                                            int* __restrict__ Sarr) {
  int lane = threadIdx.x;
  int v[5]; int s = 0;
#pragma unroll
  for (int k = 0; k < 5; ++k) {
    int i = lane * 5 + k;
    v[k] = (i < N_B) ? btot[i] : 0;
    s += v[k];
  }
  int x = s;
  for (int off = 1; off < 64; off <<= 1) {
    int tv = __shfl_up(x, off, 64);
    if (lane >= off) x += tv;
  }
  int run = x - s;
#pragma unroll
  for (int k = 0; k < 5; ++k) {
    int i = lane * 5 + k;
    if (i < N_B) bbase[i] = run;
    run += v[k];
  }
  if (lane == 63) { bbase[N_B] = x; Sarr[L_CNT] = TOTE; }
}

__global__ __launch_bounds__(256) void k_h2c(int* __restrict__ hcnt,
                                             const int* __restrict__ bbase) {
  __shared__ int sc[256];
  int b = blockIdx.x, t = threadIdx.x;
  int* c = hcnt + (size_t)b * NCH;
  int v[7]; int s = 0;
#pragma unroll
  for (int k = 0; k < 7; ++k) {
    int i = t * 7 + k;
    v[k] = (i < NCH) ? c[i] : 0;
    s += v[k];
  }
  sc[t] = s;
  __syncthreads();
  for (int off = 1; off < 256; off <<= 1) {
    int tv = (t >= off) ? sc[t - off] : 0;
    __syncthreads();
    sc[t] += tv;
    __syncthreads();
  }
  int run = bbase[b] + sc[t] - s;
#pragma unroll
  for (int k = 0; k < 7; ++k) {
    int i = t * 7 + k;
    if (i < NCH) { int vv = v[k]; c[i] = run; run += vv; }
  }
}

__global__ __launch_bounds__(256) void k_bfill(
    const int* e0, const int* e1, const int* e2, const int* e3,
    const int* e4, const int* e5, const int* e6,
    const int* __restrict__ hcnt, unsigned* __restrict__ part) {
  __shared__ int hist[N_B];
  __shared__ int segs[N_B];
  __shared__ int curb[N_B];
  __shared__ int gbase[N_B];
  __shared__ int sc[256];
  __shared__ unsigned long long stg[CHSZ];
  int ch = blockIdx.x, t = threadIdx.x;
  for (int i = t; i < N_B; i += 256) hist[i] = 0;
  __syncthreads();
  int base = ch * CHSZ;
  int nn = TOTE - base; if (nn > CHSZ) nn = CHSZ;
#pragma unroll
  for (int u = 0; u < CHSZ / 256; ++u) {
    int o = u * 256 + t;
    if (o < nn) {
      int gid = base + o;
      int et = gid / EPT, i2 = gid - et * EPT;
      const int* ei = pick(e0, e1, e2, e3, e4, e5, e6, et);
      int idx = cnt_base(et) + ei[EPT + i2];
      atomicAdd(&hist[idx >> 12], 1);
    }
  }
  __syncthreads();
  int v0 = (2 * t < N_B) ? hist[2 * t] : 0;
  int v1 = (2 * t + 1 < N_B) ? hist[2 * t + 1] : 0;
  int s = v0 + v1;
  sc[t] = s;
  __syncthreads();
  for (int off = 1; off < 256; off <<= 1) {
    int tv = (t >= off) ? sc[t - off] : 0;
    __syncthreads();
    sc[t] += tv;
    __syncthreads();
  }
  int excl = sc[t] - s;
  if (2 * t < N_B) { segs[2 * t] = excl; curb[2 * t] = excl; }
  if (2 * t + 1 < N_B) { segs[2 * t + 1] = excl + v0; curb[2 * t + 1] = excl + v0; }
  for (int b = t; b < N_B; b += 256) gbase[b] = hcnt[(size_t)b * NCH + ch];
  __syncthreads();
#pragma unroll
  for (int u = 0; u < CHSZ / 256; ++u) {
    int o = u * 256 + t;
    if (o < nn) {
      int gid = base + o;
      int et = gid / EPT, i2 = gid - et * EPT;
      const int* ei = pick(e0, e1, e2, e3, e4, e5, e6, et);
      int dst = ei[EPT + i2];
      int src = ei[i2];
      int idx = cnt_base(et) + dst;
      unsigned long long p = ((unsigned long long)idx << 32) | (unsigned)src;
      int r = atomicAdd(&curb[idx >> 12], 1);
      stg[r] = p;
    }
  }
  __syncthreads();
  for (int sdx = t; sdx < nn; sdx += 256) {
    unsigned long long p = stg[sdx];
    int idx = (int)(p >> 32);
    int b = idx >> 12;
    unsigned ent = ((unsigned)(idx & 4095) << 19) | (unsigned)(p & 0x7FFFF);
    part[(size_t)gbase[b] + (sdx - segs[b])] = ent;
  }
}

__global__ __launch_bounds__(1024) void k_cfill(
    const unsigned* __restrict__ part, const int* __restrict__ bbase,
    int* __restrict__ Sarr, int* __restrict__ col) {
  __shared__ int hist[SPAN];
  __shared__ int wt[16];
  int t = threadIdx.x;
  int lane = t & 63, wv = t >> 6;
  int b = blockIdx.x;
  int lo = b * SPAN;
  int span_n = L_CNT - lo; if (span_n > SPAN) span_n = SPAN;
  int s0 = bbase[b], s1 = bbase[b + 1];
  ((int4*)hist)[t] = (int4){0, 0, 0, 0};
  __syncthreads();
  for (int j = s0 + t; j < s1; j += 1024) {
    int local = (int)(part[j] >> 19);
    atomicAdd(&hist[local], 1);
  }
  __syncthreads();
  int4 v = ((int4*)hist)[t];
  int s = v.x + v.y + v.z + v.w;
  int x = s;
#pragma unroll
  for (int off = 1; off < 64; off <<= 1) {
    int tv = __shfl_up(x, off, 64);
    if (lane >= off) x += tv;
  }
  if (lane == 63) wt[wv] = x;
  __syncthreads();
  int woff = 0;
#pragma unroll
  for (int k = 0; k < 16; ++k) woff += (k < wv) ? wt[k] : 0;
  int run = woff + x - s;
  int4 cur4, sa4;
  cur4.x = run; sa4.x = s0 + run; run += v.x;
  cur4.y = run; sa4.y = s0 + run; run += v.y;
  cur4.z = run; sa4.z = s0 + run; run += v.z;
  cur4.w = run; sa4.w = s0 + run; run += v.w;
  __syncthreads();
  ((int4*)hist)[t] = cur4;
  if (t * 4 + 3 < span_n) {
    *(int4*)(&Sarr[lo + t * 4]) = sa4;
  } else {
    if (t * 4 + 0 < span_n) Sarr[lo + t * 4 + 0] = sa4.x;
    if (t * 4 + 1 < span_n) Sarr[lo + t * 4 + 1] = sa4.y;
    if (t * 4 + 2 < span_n) Sarr[lo + t * 4 + 2] = sa4.z;
  }
  __syncthreads();
  for (int j = s0 + t; j < s1; j += 1024) {
    unsigned p = part[j];
    int local = (int)(p >> 19);
    int r = atomicAdd(&hist[local], 1);
    col[s0 + r] = (int)(p & 0x7FFFF);
  }
}

// ---------------- weight prep (fold + swizzle -> bf16) ----------------
template <int KIN, int NE>
__global__ __launch_bounds__(256) void k_prep(
    const float* __restrict__ Wl, const float* __restrict__ Wr,
    const float* __restrict__ bl, int e0, int e1, int e2, int es,
    unsigned short* __restrict__ wsw, float* __restrict__ bias) {
  constexpr int KCAT = (NE + 1) * KIN;
  int idx = blockIdx.x * 256 + threadIdx.x;
  if (idx < KCAT * 64) {
    int j = idx & 7, lane = (idx >> 3) & 63, t = idx >> 9;
    int ct = t & 3, kc = t >> 2;
    int k = kc * 32 + ((lane >> 4) << 3) + j;
    int c = ct * 16 + (lane & 15);
    int seg = k / KIN, kk = k - seg * KIN;
    float v;
    if (seg < NE) {
      int e = (seg == 0) ? e0 : (seg == 1) ? e1 : e2;
      v = Wl[((size_t)e * 64 + c) * KIN + kk];
    } else {
      v = Wl[((size_t)es * 64 + c) * KIN + kk] +
          Wr[((size_t)es * 64 + c) * KIN + kk] +
          Wr[((size_t)e0 * 64 + c) * KIN + kk] +
          Wr[((size_t)e1 * 64 + c) * KIN + kk];
      if (NE == 3) v += Wr[((size_t)e2 * 64 + c) * KIN + kk];
    }
    wsw[idx] = f2bf(v);
  } else if (idx < KCAT * 64 + 64) {
    int c = idx - KCAT * 64;
    float v = bl[e0 * 64 + c] + bl[e1 * 64 + c] + bl[es * 64 + c];
    if (NE == 3) v += bl[e2 * 64 + c];
    bias[c] = v;
  }
}

// ------- fused 3-dst-type layer: gather(mean) + MFMA + epilogue -------
// Gather = R10's serial-chain branch-free loop (R11 lesson: lockstep chains
// regressed 2.2x -- divergent branchy bodies defeat load pipelining).
// One launch per layer: tile index -> dst type by range (pf/sw tiles overlap
// the big gw work instead of serializing behind it).
struct LType {
  const unsigned short* s0;
  const unsigned short* s1;
  const unsigned short* s2;
  int b0, b1, b2, ne;
  const unsigned short* xD;
  const unsigned short* wsw;
  const float* bias;
  void* hOut;
  int omode;   // 0 bf16 h, 1 f32 h, 2 fused linear+PReLU
  int ntile;   // Ndst/16
};

template <int KIN>
__global__ __launch_bounds__(256) void k_layerF(
    const int* __restrict__ Sarr, const int* __restrict__ col, LType t0,
    LType t1, LType t2, const float* __restrict__ linW,
    const float* __restrict__ linb, const float* __restrict__ pa) {
  constexpr int ZSTR = 4 * KIN + 8;   // max (ne=3) layout, 16B-aligned rows
  constexpr int LPR = KIN / 8;        // lanes per feature row (8 or 4)
  constexpr int G = 64 / LPR;         // node-groups per wave (8 or 16)
  __shared__ unsigned short z[4 * 16 * ZSTR];
  const int lane = threadIdx.x & 63;
  unsigned short* zw = &z[(threadIdx.x >> 6) * 16 * ZSTR];
  const int wid = (blockIdx.x * 256 + threadIdx.x) >> 6;
  const int nw = (gridDim.x * 256) >> 6;
  const int cl = lane & 15, quad = lane >> 4;
  const int g = lane / LPR;
  const int c = lane % LPR;
  const int TT = t0.ntile + t1.ntile + t2.ntile;

  for (int tile = wid; tile < TT; tile += nw) {
    LType tp;
    int lt = tile;
    if (lt < t0.ntile) tp = t0;
    else if ((lt -= t0.ntile) < t1.ntile) tp = t1;
    else { lt -= t1.ntile; tp = t2; }
    const int nb = lt * 16;
    const int ne = tp.ne;
    const int kchr = (ne + 1) * (KIN / 32);

    // ---- gather: serial chains per (node-group, e); branch-free body ----
#pragma unroll
    for (int i0 = 0; i0 < 16; i0 += G) {
      int n = nb + i0 + g;
      unsigned short* zr = &zw[(i0 + g) * ZSTR];
      *(short8*)(&zr[ne * KIN + c * 8]) =
          *(const short8*)(tp.xD + (size_t)n * KIN + c * 8);
      for (int e = 0; e < ne; ++e) {
        const unsigned short* se = (e == 0) ? tp.s0 : (e == 1) ? tp.s1 : tp.s2;
        int be = (e == 0) ? tp.b0 : (e == 1) ? tp.b1 : tp.b2;
        int s = Sarr[be + n];
        int t = Sarr[be + n + 1];  // sentinel-safe
        float a0[8] = {0, 0, 0, 0, 0, 0, 0, 0};
        float a1[8] = {0, 0, 0, 0, 0, 0, 0, 0};
        int j = s;
        for (; j + 1 < t; j += 2) {
          int r0 = col[j], r1 = col[j + 1];
          short8 v0 = *(const short8*)(se + (size_t)r0 * KIN + c * 8);
          short8 v1 = *(const short8*)(se + (size_t)r1 * KIN + c * 8);
          acc8(a0, v0);
          acc8(a1, v1);
        }
        if (j < t) {
          int r0 = col[j];
          short8 v0 = *(const short8*)(se + (size_t)r0 * KIN + c * 8);
          acc8(a0, v0);
        }
        int cv = t - s;
        if (cv < 1) cv = 1;
        float inv = 1.0f / (float)cv;
        short8 o;
#pragma unroll
        for (int k = 0; k < 8; ++k)
          o[k] = (short)f2bf((a0[k] + a1[k]) * inv);
        *(short8*)(&zr[e * KIN + c * 8]) = o;
      }
    }
    // ---- MFMA: 16 nodes x 64 out cols, K = (ne+1)*KIN ----
    floatx4 acc[4];
#pragma unroll
    for (int ct = 0; ct < 4; ++ct) {
      float bv = tp.bias[ct * 16 + cl];
      acc[ct] = (floatx4){bv, bv, bv, bv};
    }
    for (int kc = 0; kc < kchr; ++kc) {
      short8 a = *(const short8*)(&zw[cl * ZSTR + kc * 32 + quad * 8]);
#pragma unroll
      for (int ct = 0; ct < 4; ++ct) {
        short8 b =
            *(const short8*)(tp.wsw + ((size_t)(kc * 4 + ct) * 64 + lane) * 8);
        acc[ct] = __builtin_amdgcn_mfma_f32_16x16x32_bf16(a, b, acc[ct], 0, 0, 0);
      }
    }
    // ---- epilogue ----
    if (tp.omode == 2) {
      float p[4] = {0.f, 0.f, 0.f, 0.f};
#pragma unroll
      for (int ct = 0; ct < 4; ++ct) {
        float w = linW[ct * 16 + cl];
#pragma unroll
        for (int r = 0; r < 4; ++r) {
          float v = acc[ct][r];
          v = v > 0.f ? v : 0.f;
          p[r] += v * w;
        }
      }
#pragma unroll
      for (int off = 1; off < 16; off <<= 1) {
#pragma unroll
        for (int r = 0; r < 4; ++r) p[r] += __shfl_xor(p[r], off, 64);
      }
      if (cl == 0) {
        float lb = linb[0], al = pa[0];
        float* o = (float*)tp.hOut;
#pragma unroll
        for (int r = 0; r < 4; ++r) {
          int n = nb + quad * 4 + r;
          float v = p[r] + lb;
          o[n] = v >= 0.f ? v : al * v;
        }
      }
    } else if (tp.omode == 1) {
#pragma unroll
      for (int ct = 0; ct < 4; ++ct)
#pragma unroll
        for (int r = 0; r < 4; ++r) {
          int n = nb + quad * 4 + r;
          float v = acc[ct][r];
          ((float*)tp.hOut)[(size_t)n * 64 + ct * 16 + cl] = v > 0.f ? v : 0.f;
        }
    } else {
#pragma unroll
      for (int ct = 0; ct < 4; ++ct)
#pragma unroll
        for (int r = 0; r < 4; ++r) {
          int n = nb + quad * 4 + r;
          float v = acc[ct][r];
          ((unsigned short*)tp.hOut)[(size_t)n * 64 + ct * 16 + cl] =
              f2bf(v > 0.f ? v : 0.f);
        }
    }
  }
}

extern "C" void kernel_launch(void* const* d_in, const int* in_sizes, int n_in,
                              void* d_out, int out_size, void* d_ws,
                              size_t ws_size, hipStream_t stream) {
  const float* x_pf = (const float*)d_in[0];
  const float* x_gw = (const float*)d_in[1];
  const float* x_sw = (const float*)d_in[2];
  const float* W1l = (const float*)d_in[3];
  const float* b1l = (const float*)d_in[4];
  const float* W1r = (const float*)d_in[5];
  const float* W2l = (const float*)d_in[6];
  const float* b2l = (const float*)d_in[7];
  const float* W2r = (const float*)d_in[8];
  const float* linW = (const float*)d_in[9];
  const float* linb = (const float*)d_in[10];
  const float* pa = (const float*)d_in[11];
  const int* e0 = (const int*)d_in[12];  // pf->gw
  const int* e1 = (const int*)d_in[13];  // gw->pf
  const int* e2 = (const int*)d_in[14];  // pf->sw
  const int* e3 = (const int*)d_in[15];  // sw->pf
  const int* e4 = (const int*)d_in[16];  // sw->gw
  const int* e5 = (const int*)d_in[17];  // gw->sw
  const int* e6 = (const int*)d_in[18];  // gw->gw
  float* out = (float*)d_out;

  char* w = (char*)d_ws;
  size_t off = 0;
  auto alloc = [&](size_t bytes) -> void* {
    void* p = w + off;
    off += bytes;
    off = (off + 255) & ~(size_t)255;
    return p;
  };
  unsigned* part = (unsigned*)alloc((size_t)TOTE * 4);
  int* col = (int*)alloc((size_t)TOTE * 4);
  int* Sarr = (int*)alloc((size_t)(L_CNT + 1) * 4);
  int* hcnt = (int*)alloc((size_t)N_B * NCH * 4);
  int* btot = (int*)alloc((N_B + 1) * 4);
  int* bbase = (int*)alloc((N_B + 1) * 4);
  unsigned short* xb_pf = (unsigned short*)alloc((size_t)N_PF * 32 * 2);
  unsigned short* xb_gw = (unsigned short*)alloc((size_t)N_GW * 32 * 2);
  unsigned short* xb_sw = (unsigned short*)alloc((size_t)N_SW * 32 * 2);
  unsigned short* h1_pf = (unsigned short*)alloc((size_t)N_PF * 64 * 2);
  unsigned short* h1_gw = (unsigned short*)alloc((size_t)N_GW * 64 * 2);
  unsigned short* h1_sw = (unsigned short*)alloc((size_t)N_SW * 64 * 2);
  unsigned short* w1gw = (unsigned short*)alloc(128 * 64 * 2);
  unsigned short* w1pf = (unsigned short*)alloc(96 * 64 * 2);
  unsigned short* w1sw = (unsigned short*)alloc(96 * 64 * 2);
  unsigned short* w2gw = (unsigned short*)alloc(256 * 64 * 2);
  unsigned short* w2pf = (unsigned short*)alloc(192 * 64 * 2);
  unsigned short* w2sw = (unsigned short*)alloc(192 * 64 * 2);
  float* bs1gw = (float*)alloc(64 * 4);
  float* bs1pf = (float*)alloc(64 * 4);
  float* bs1sw = (float*)alloc(64 * 4);
  float* bs2gw = (float*)alloc(64 * 4);
  float* bs2pf = (float*)alloc(64 * 4);
  float* bs2sw = (float*)alloc(64 * 4);

  // input casts
  k_cast<<<(N_PF * 8 + 255) / 256, 256, 0, stream>>>((const float4*)x_pf,
                                                     (ushort4*)xb_pf, N_PF * 8);
  k_cast<<<(N_GW * 8 + 255) / 256, 256, 0, stream>>>((const float4*)x_gw,
                                                     (ushort4*)xb_gw, N_GW * 8);
  k_cast<<<(N_SW * 8 + 255) / 256, 256, 0, stream>>>((const float4*)x_sw,
                                                     (ushort4*)xb_sw, N_SW * 8);

  // CSR build: radix partition
  k_h1<<<NCH, 256, 0, stream>>>(e0, e1, e2, e3, e4, e5, e6, hcnt);
  k_h2a<<<N_B, 256, 0, stream>>>(hcnt, btot);
  k_h2b<<<1, 64, 0, stream>>>(btot, bbase, Sarr);
  k_h2c<<<N_B, 256, 0, stream>>>(hcnt, bbase);
  k_bfill<<<NCH, 256, 0, stream>>>(e0, e1, e2, e3, e4, e5, e6, hcnt, part);
  k_cfill<<<N_B, 1024, 0, stream>>>(part, bbase, Sarr, col);

  // weight prep
  k_prep<32, 3><<<(128 * 64 + 64 + 255) / 256, 256, 0, stream>>>(
      W1l, W1r, b1l, 0, 4, 6, 7, w1gw, bs1gw);
  k_prep<32, 2><<<(96 * 64 + 64 + 255) / 256, 256, 0, stream>>>(
      W1l, W1r, b1l, 1, 3, 0, 9, w1pf, bs1pf);
  k_prep<32, 2><<<(96 * 64 + 64 + 255) / 256, 256, 0, stream>>>(
      W1l, W1r, b1l, 2, 5, 0, 8, w1sw, bs1sw);
  k_prep<64, 3><<<(256 * 64 + 64 + 255) / 256, 256, 0, stream>>>(
      W2l, W2r, b2l, 0, 4, 6, 7, w2gw, bs2gw);
  k_prep<64, 2><<<(192 * 64 + 64 + 255) / 256, 256, 0, stream>>>(
      W2l, W2r, b2l, 1, 3, 0, 9, w2pf, bs2pf);
  k_prep<64, 2><<<(192 * 64 + 64 + 255) / 256, 256, 0, stream>>>(
      W2l, W2r, b2l, 2, 5, 0, 8, w2sw, bs2sw);

  // layer 1 (KIN=32): one fused launch for gw/pf/sw
  LType a0{xb_pf, xb_sw, xb_gw, 0, 480000, 840000, 3,
           xb_gw, w1gw, bs1gw, h1_gw, 0, N_GW / 16};
  LType a1{xb_gw, xb_sw, nullptr, 300000, 420000, 0, 2,
           xb_pf, w1pf, bs1pf, h1_pf, 0, N_PF / 16};
  LType a2{xb_pf, xb_gw, nullptr, 360000, 780000, 0, 2,
           xb_sw, w1sw, bs1sw, h1_sw, 0, N_SW / 16};
  k_layerF<32><<<1024, 256, 0, stream>>>(Sarr, col, a0, a1, a2, linW, linb, pa);

  // layer 2 (KIN=64): one fused launch; gw/sw fuse linear+PReLU, pf -> f32
  LType c0{h1_pf, h1_sw, h1_gw, 0, 480000, 840000, 3,
           h1_gw, w2gw, bs2gw, out, 2, N_GW / 16};
  LType c1{h1_gw, h1_sw, nullptr, 300000, 420000, 0, 2,
           h1_pf, w2pf, bs2pf, out + 360000, 1, N_PF / 16};
  LType c2{h1_pf, h1_gw, nullptr, 360000, 780000, 0, 2,
           h1_sw, w2sw, bs2sw, out + N_GW, 2, N_SW / 16};
  k_layerF<64><<<1024, 256, 0, stream>>>(Sarr, col, c0, c1, c2, linW, linb, pa);
}